// Round 1
// baseline (36.091 us; speedup 1.0000x reference)
//
#include <hip/hip_runtime.h>
#include <stdint.h>

// SNN 50-step integrate-fire spike encoding.
// x: [256,1,4096] f32 -> out: [256,1,4096,50] f32 (0/1 spikes).
// elem = b*4096+f; out[elem*50 + t].
//
// Phase 1: each thread runs the exact reference f32 recurrence for its
//          element, packing the 50 binary spikes into a uint64.
// Phase 2: block-cooperative coalesced float4 writes of the block's
//          contiguous 256*50-float output region, unpacking bits from LDS.

#define TIME 50
#define BLOCK 256
#define REGION (BLOCK * TIME)  // 12800 floats per block, contiguous

__global__ __launch_bounds__(BLOCK) void snn_encode_kernel(
    const float* __restrict__ x, float* __restrict__ out, int n_elems) {
    __shared__ unsigned long long sb[BLOCK];  // 2 KB: spike bitmasks

    const int tid = threadIdx.x;
    const int elem = blockIdx.x * BLOCK + tid;

    // ---- Phase 1: serial 50-step recurrence (exact reference semantics) ----
    unsigned long long bits = 0ull;
    if (elem < n_elems) {
        const float cur = x[elem] * 1.0f + 1.0f;  // SCALE=1, OFFSET=1
        float v = 0.0f;
        float th = 0.5f;  // THRESH_ENC
        #pragma unroll
        for (int t = 0; t < TIME; ++t) {
            v += cur;                         // integrate (f32 add, same as ref)
            const bool s = (v >= th);         // fire
            if (s) {
                v = 0.0f;                     // reset (leak = 1.0)
                th += 0.03f;                  // THRESH_PLUS adaptation
                bits |= (1ull << t);
            }
        }
    }
    sb[tid] = bits;
    __syncthreads();

    // ---- Phase 2: coalesced float4 writeout of this block's region ----
    float* dst = out + (size_t)blockIdx.x * REGION;
    // (full blocks only: n_elems = 256*4096 is a multiple of BLOCK)
    for (int k = tid * 4; k < REGION; k += BLOCK * 4) {
        float vals[4];
        #pragma unroll
        for (int i = 0; i < 4; ++i) {
            const int j = k + i;
            const int e = j / TIME;           // magic-mul div by 50
            const int t = j - e * TIME;
            vals[i] = (float)((sb[e] >> t) & 1ull);
        }
        *reinterpret_cast<float4*>(dst + k) =
            make_float4(vals[0], vals[1], vals[2], vals[3]);
    }
}

extern "C" void kernel_launch(void* const* d_in, const int* in_sizes, int n_in,
                              void* d_out, int out_size, void* d_ws, size_t ws_size,
                              hipStream_t stream) {
    const float* x = (const float*)d_in[0];
    float* out = (float*)d_out;
    const int n = in_sizes[0];               // 256*1*4096 = 1,048,576 elements
    const int blocks = (n + BLOCK - 1) / BLOCK;  // 4096
    snn_encode_kernel<<<blocks, BLOCK, 0, stream>>>(x, out, n);
}